// Round 1
// baseline (2927.785 us; speedup 1.0000x reference)
//
#include <hip/hip_runtime.h>
#include <hip/hip_bf16.h>

// EarthAttention2D on MI355X (gfx950).
// B_WIN=2048, N=128, DIM=512, HEADS=16, hd=32, M = 2048*128 = 262144.
// Pipeline: prep (weights->bf16, epb gather) -> QKV GEMM (bf16 MFMA) ->
//           fused window attention -> proj GEMM (f32 out).

typedef short short8 __attribute__((ext_vector_type(8)));
typedef float f32x4 __attribute__((ext_vector_type(4)));
typedef unsigned short u16;
typedef unsigned int u32;

__device__ __forceinline__ u16 f2bf(float f) {
    __bf16 h = (__bf16)f;                    // RNE fptrunc -> v_cvt on gfx950
    union { __bf16 b; u16 u; } v; v.b = h;
    return v.u;
}

__device__ __forceinline__ f32x4 mfma16(short8 a, short8 b, f32x4 c) {
    return __builtin_amdgcn_mfma_f32_16x16x32_bf16(a, b, c, 0, 0, 0);
}

// ---------------------------------------------------------------- prep ----
// i in [0, 786432): qkv_w -> bf16 ; i < 262144: proj_w -> bf16 and epb gather
__global__ __launch_bounds__(256) void prep_kernel(
    const float* __restrict__ qkv_w, const float* __restrict__ proj_w,
    const float* __restrict__ btab, const int* __restrict__ pidx,
    u16* __restrict__ qkvw_bf, u16* __restrict__ projw_bf,
    float* __restrict__ epb)
{
    const int i = blockIdx.x * 256 + threadIdx.x;    // grid = 3072*256 = 786432
    qkvw_bf[i] = f2bf(qkv_w[i]);
    if (i < 512 * 512) projw_bf[i] = f2bf(proj_w[i]);
    if (i < 16 * 128 * 128) {
        const int rc = i & 16383, h = i >> 14;
        epb[i] = btab[pidx[rc] * 128 + 64 + h];      // bias_table[idx][TOW/2=4][h]
    }
}

// ---------------------------------------------------------------- GEMM ----
// C[M,Nn] = A[M,K] @ Bt[Nn,K]^T (+bias).  128x128 tile, BK=64, 256 thr.
// LDS tiles XOR-swizzled (T2: byte ^= (row&7)<<4) -> conflict-free ds_read_b128.
// AF32: A is fp32, converted to bf16 while staging (needed for x).
// EPI_QKV: +bias, *qscale for cols<512, bf16 out restaged via LDS for int4 stores.
// else:    +bias, f32 direct stores.
template<bool AF32, bool EPI_QKV>
__global__ __launch_bounds__(256) void gemm_bt(
    const void* __restrict__ Av, const u16* __restrict__ Bt,
    const float* __restrict__ bias, void* __restrict__ Cv,
    const int Nn, const int K, const float qscale)
{
    __shared__ __attribute__((aligned(16))) u16 smem[2 * 128 * 64];
    u16* As = smem;
    u16* Bs = smem + 128 * 64;

    const int tid = threadIdx.x;
    const int lane = tid & 63;
    const int w = tid >> 6;
    const int lo = lane & 15, g = lane >> 4;
    const int wm = w >> 1, wn = w & 1;
    const int ntile = Nn >> 7;

    int wg = blockIdx.x;
    {   // bijective XCD swizzle (gridDim % 8 == 0 for both launches)
        const int cpx = gridDim.x >> 3;
        wg = (wg & 7) * cpx + (wg >> 3);
    }
    const int bm = wg / ntile, bn = wg % ntile;
    const size_t m0 = (size_t)bm << 7;
    const int n0 = bn << 7;
    const int nk = K >> 6;

    const float* Af = (const float*)Av;
    const u16*   Ah = (const u16*)Av;

    float4 a4[8];
    int4   ah4[4];
    int4   b4[4];

    auto loadA = [&](int kt) {
        if constexpr (AF32) {
            const float* p = Af + (m0 + (tid >> 1)) * (size_t)K + kt * 64 + (tid & 1) * 32;
#pragma unroll
            for (int i = 0; i < 8; ++i) a4[i] = *(const float4*)(p + i * 4);
        } else {
#pragma unroll
            for (int i = 0; i < 4; ++i) {
                const int idx = tid + i * 256;
                ah4[i] = *(const int4*)(Ah + (m0 + (idx >> 3)) * (size_t)K + kt * 64 + (idx & 7) * 8);
            }
        }
    };
    auto loadB = [&](int kt) {
#pragma unroll
        for (int i = 0; i < 4; ++i) {
            const int idx = tid + i * 256;
            b4[i] = *(const int4*)(Bt + (size_t)(n0 + (idx >> 3)) * K + kt * 64 + (idx & 7) * 8);
        }
    };
    auto storeA = [&]() {
        if constexpr (AF32) {
            const int r = tid >> 1, cb0 = (tid & 1) * 64;
            const int sz = (r & 7) << 4;
#pragma unroll
            for (int i = 0; i < 8; ++i) {
                uint2 pk;
                pk.x = (u32)f2bf(a4[i].x) | ((u32)f2bf(a4[i].y) << 16);
                pk.y = (u32)f2bf(a4[i].z) | ((u32)f2bf(a4[i].w) << 16);
                *(uint2*)((char*)As + ((r * 128 + cb0 + i * 8) ^ sz)) = pk;
            }
        } else {
#pragma unroll
            for (int i = 0; i < 4; ++i) {
                const int idx = tid + i * 256;
                const int r = idx >> 3, cb = (idx & 7) * 16;
                *(int4*)((char*)As + ((r * 128 + cb) ^ ((r & 7) << 4))) = ah4[i];
            }
        }
    };
    auto storeB = [&]() {
#pragma unroll
        for (int i = 0; i < 4; ++i) {
            const int idx = tid + i * 256;
            const int r = idx >> 3, cb = (idx & 7) * 16;
            *(int4*)((char*)Bs + ((r * 128 + cb) ^ ((r & 7) << 4))) = b4[i];
        }
    };

    f32x4 acc[4][4] = {};

    loadA(0); loadB(0);
    for (int kt = 0; kt < nk; ++kt) {
        storeA(); storeB();
        __syncthreads();
        if (kt + 1 < nk) { loadA(kt + 1); loadB(kt + 1); }   // overlap next loads with MFMA
#pragma unroll
        for (int kk = 0; kk < 2; ++kk) {
            short8 af[4], bfr[4];
            const int cb = (kk * 32 + g * 8) * 2;
            const int sz = (lo & 7) << 4;   // rows are base(mult of 16)+lo -> r&7 == lo&7
#pragma unroll
            for (int i = 0; i < 4; ++i) {
                const int r = wm * 64 + i * 16 + lo;
                af[i] = *(const short8*)((const char*)As + ((r * 128 + cb) ^ sz));
            }
#pragma unroll
            for (int j = 0; j < 4; ++j) {
                const int r = wn * 64 + j * 16 + lo;
                bfr[j] = *(const short8*)((const char*)Bs + ((r * 128 + cb) ^ sz));
            }
#pragma unroll
            for (int i = 0; i < 4; ++i)
#pragma unroll
                for (int j = 0; j < 4; ++j)
                    acc[i][j] = mfma16(af[i], bfr[j], acc[i][j]);
        }
        __syncthreads();
    }

    if constexpr (EPI_QKV) {
        // restage C tile (128x128 bf16 = 32 KiB = exactly As+Bs) for coalesced stores
        u16* Ct = smem;
#pragma unroll
        for (int j = 0; j < 4; ++j) {
            const int c = wn * 64 + j * 16 + lo;
            const float bv = bias[n0 + c];
            const float sc = (n0 + c < 512) ? qscale : 1.0f;
#pragma unroll
            for (int i = 0; i < 4; ++i)
#pragma unroll
                for (int ii = 0; ii < 4; ++ii) {
                    const int r = wm * 64 + i * 16 + g * 4 + ii;
                    Ct[r * 128 + c] = f2bf((acc[i][j][ii] + bv) * sc);
                }
        }
        __syncthreads();
        u16* Cg = (u16*)Cv;
#pragma unroll
        for (int it = 0; it < 8; ++it) {
            const int idx = tid + it * 256;
            const int r = idx >> 4, sgm = idx & 15;
            *(int4*)(Cg + (m0 + r) * (size_t)Nn + n0 + sgm * 8) =
                *(const int4*)(Ct + r * 128 + sgm * 8);
        }
    } else {
        float* Cg = (float*)Cv;
#pragma unroll
        for (int j = 0; j < 4; ++j) {
            const int c = wn * 64 + j * 16 + lo;
            const float bv = bias[n0 + c];
#pragma unroll
            for (int i = 0; i < 4; ++i)
#pragma unroll
                for (int ii = 0; ii < 4; ++ii) {
                    const int r = wm * 64 + i * 16 + g * 4 + ii;
                    Cg[(m0 + r) * (size_t)Nn + n0 + c] = acc[i][j][ii] + bv;
                }
        }
    }
}

// ----------------------------------------------------------- attention ----
// One block (4 waves) per (b, h). qkv layout: [b*128+n][t*512 + h*32 + d].
// Wave w owns S rows [w*32, w*32+32). S = Q@K^T (q pre-scaled) + epb[h].
// Softmax per row: 8 col-tiles in-lane + shfl_xor reduce over 16 lanes.
// P staged bf16 in padded LDS -> PV MFMA, normalize in epilogue.
__global__ __launch_bounds__(256) void attn_kernel(
    const u16* __restrict__ qkv, const float* __restrict__ epb,
    u16* __restrict__ aout)
{
    __shared__ __attribute__((aligned(16))) u16 Qs[128][32];
    __shared__ __attribute__((aligned(16))) u16 Ks[128][32];
    __shared__ __attribute__((aligned(16))) u16 Vt[32][136];   // V^T, padded
    __shared__ __attribute__((aligned(16))) u16 Ps[4][32][136];

    const int h = blockIdx.x >> 11;
    const int b = blockIdx.x & 2047;
    const int tid = threadIdx.x;
    const int lane = tid & 63, w = tid >> 6;
    const int lo = lane & 15, g = lane >> 4;

    const size_t base = (size_t)b * 128 * 1536 + h * 32;
#pragma unroll
    for (int it = 0; it < 2; ++it) {
        const int s = tid + it * 256;            // 0..511
        const int n = s >> 2, c = (s & 3) * 8;
        const u16* p = qkv + base + (size_t)n * 1536 + c;
        *(int4*)(&Qs[n][c]) = *(const int4*)(p);
        *(int4*)(&Ks[n][c]) = *(const int4*)(p + 512);
        union { int4 q; u16 u[8]; } vu;
        vu.q = *(const int4*)(p + 1024);
#pragma unroll
        for (int j = 0; j < 8; ++j) Vt[c + j][n] = vu.u[j];
    }
    __syncthreads();

    const int r0 = w * 32;

    // ---- S = Q @ K^T ----
    short8 aq[2];
    aq[0] = *(const short8*)(&Qs[r0 + lo][g * 8]);
    aq[1] = *(const short8*)(&Qs[r0 + 16 + lo][g * 8]);
    f32x4 acc[2][8];
#pragma unroll
    for (int j = 0; j < 8; ++j) {
        const short8 bk = *(const short8*)(&Ks[j * 16 + lo][g * 8]);
        f32x4 z = {0.f, 0.f, 0.f, 0.f};
        acc[0][j] = mfma16(aq[0], bk, z);
        acc[1][j] = mfma16(aq[1], bk, z);
    }

    // ---- bias + softmax ----
    const float* eb = epb + (h << 14);
    float mrow[2][4], rsum[2][4];
#pragma unroll
    for (int mt = 0; mt < 2; ++mt)
#pragma unroll
        for (int ii = 0; ii < 4; ++ii) { mrow[mt][ii] = -1e30f; rsum[mt][ii] = 0.f; }

#pragma unroll
    for (int mt = 0; mt < 2; ++mt)
#pragma unroll
        for (int j = 0; j < 8; ++j)
#pragma unroll
            for (int ii = 0; ii < 4; ++ii) {
                const int r = r0 + mt * 16 + g * 4 + ii;
                const int c = j * 16 + lo;
                const float sv = acc[mt][j][ii] + eb[(r << 7) + c];
                acc[mt][j][ii] = sv;
                mrow[mt][ii] = fmaxf(mrow[mt][ii], sv);
            }
#pragma unroll
    for (int d = 1; d < 16; d <<= 1)
#pragma unroll
        for (int mt = 0; mt < 2; ++mt)
#pragma unroll
            for (int ii = 0; ii < 4; ++ii)
                mrow[mt][ii] = fmaxf(mrow[mt][ii], __shfl_xor(mrow[mt][ii], d, 64));

#pragma unroll
    for (int mt = 0; mt < 2; ++mt)
#pragma unroll
        for (int j = 0; j < 8; ++j)
#pragma unroll
            for (int ii = 0; ii < 4; ++ii) {
                const float p = __expf(acc[mt][j][ii] - mrow[mt][ii]);
                rsum[mt][ii] += p;
                Ps[w][mt * 16 + g * 4 + ii][j * 16 + lo] = f2bf(p);
            }
#pragma unroll
    for (int d = 1; d < 16; d <<= 1)
#pragma unroll
        for (int mt = 0; mt < 2; ++mt)
#pragma unroll
            for (int ii = 0; ii < 4; ++ii)
                rsum[mt][ii] += __shfl_xor(rsum[mt][ii], d, 64);

    // ---- O = P @ V ----  (per-wave private Ps region; no barrier needed)
    f32x4 o[2][2] = {};
#pragma unroll
    for (int kk = 0; kk < 4; ++kk) {
        short8 av[2];
        av[0] = *(const short8*)(&Ps[w][lo][kk * 32 + g * 8]);
        av[1] = *(const short8*)(&Ps[w][16 + lo][kk * 32 + g * 8]);
#pragma unroll
        for (int dt = 0; dt < 2; ++dt) {
            const short8 bv = *(const short8*)(&Vt[dt * 16 + lo][kk * 32 + g * 8]);
            o[0][dt] = mfma16(av[0], bv, o[0][dt]);
            o[1][dt] = mfma16(av[1], bv, o[1][dt]);
        }
    }

    // ---- epilogue: normalize, write [b*128+n][h*32+d] bf16 ----
    u16* op = aout + (size_t)b * 128 * 512 + h * 32;
#pragma unroll
    for (int mt = 0; mt < 2; ++mt)
#pragma unroll
        for (int dt = 0; dt < 2; ++dt)
#pragma unroll
            for (int ii = 0; ii < 4; ++ii) {
                const int r = r0 + mt * 16 + g * 4 + ii;
                const int d = dt * 16 + lo;
                op[(size_t)r * 512 + d] = f2bf(o[mt][dt][ii] / rsum[mt][ii]);
            }
}

// -------------------------------------------------------------- launch ----
extern "C" void kernel_launch(void* const* d_in, const int* in_sizes, int n_in,
                              void* d_out, int out_size, void* d_ws, size_t ws_size,
                              hipStream_t stream)
{
    const float* x      = (const float*)d_in[0];
    const float* qkv_w  = (const float*)d_in[1];
    const float* qkv_b  = (const float*)d_in[2];
    const float* proj_w = (const float*)d_in[3];
    const float* proj_b = (const float*)d_in[4];
    const float* btab   = (const float*)d_in[5];
    const int*   pidx   = (const int*)d_in[6];

    // workspace layout (bytes), total ~1.003 GiB
    char* ws = (char*)d_ws;
    u16*   qkvw_bf = (u16*)(ws);                         //  1,572,864
    u16*   projw_bf = (u16*)(ws + 1572864);              //    524,288
    float* epb      = (float*)(ws + 2097152);            //  1,048,576
    u16*   qkvbuf   = (u16*)(ws + 3145728);              // 805,306,368
    u16*   attnbuf  = (u16*)(ws + 808452096);            // 268,435,456

    const float qscale = 0.17677669529663687f;           // 32^-0.5

    prep_kernel<<<dim3(3072), dim3(256), 0, stream>>>(
        qkv_w, proj_w, btab, pidx, qkvw_bf, projw_bf, epb);

    // QKV: [262144,512]f32 @ [1536,512]bf16^T -> bf16 (+bias, q*scale)
    gemm_bt<true, true><<<dim3(2048 * 12), dim3(256), 0, stream>>>(
        x, qkvw_bf, qkv_b, qkvbuf, 1536, 512, qscale);

    // fused window attention: 2048 windows x 16 heads
    attn_kernel<<<dim3(32768), dim3(256), 0, stream>>>(qkvbuf, epb, attnbuf);

    // proj: [262144,512]bf16 @ [512,512]bf16^T -> f32 (+bias)
    gemm_bt<false, false><<<dim3(2048 * 4), dim3(256), 0, stream>>>(
        attnbuf, projw_bf, proj_b, d_out, 512, 512, 1.0f);
}

// Round 2
// 1355.472 us; speedup vs baseline: 2.1600x; 2.1600x over previous
//
#include <hip/hip_runtime.h>
#include <hip/hip_bf16.h>

// EarthAttention2D on MI355X (gfx950).
// B_WIN=2048, N=128, DIM=512, HEADS=16, hd=32, M = 2048*128 = 262144.
// Pipeline: cvt_x (x->bf16) + prep (weights->bf16, epb gather)
//        -> QKV GEMM (m97-style: global_load_lds + swizzled LDS, bf16 MFMA)
//        -> fused window attention (union LDS, 3 blocks/CU)
//        -> proj GEMM (f32 out).

typedef short short8 __attribute__((ext_vector_type(8)));
typedef float f32x4 __attribute__((ext_vector_type(4)));
typedef unsigned short u16;
typedef unsigned int u32;

__device__ __forceinline__ u16 f2bf(float f) {
    __bf16 h = (__bf16)f;                    // RNE fptrunc -> v_cvt on gfx950
    union { __bf16 b; u16 u; } v; v.b = h;
    return v.u;
}

__device__ __forceinline__ f32x4 mfma16(short8 a, short8 b, f32x4 c) {
    return __builtin_amdgcn_mfma_f32_16x16x32_bf16(a, b, c, 0, 0, 0);
}

// async global->LDS, 16B per lane, dest = wave-uniform base + lane*16
#define GLDS16(gsrc, ldst)                                                  \
    __builtin_amdgcn_global_load_lds(                                       \
        (const __attribute__((address_space(1))) void*)(gsrc),              \
        (__attribute__((address_space(3))) void*)(ldst), 16, 0, 0)

// ---------------------------------------------------------------- cvt_x ----
// 134217728 floats -> bf16, 8 per thread. grid 8192*256, 8 units each.
__global__ __launch_bounds__(256) void cvt_x_kernel(
    const float4* __restrict__ xin, int4* __restrict__ xbf)
{
    int idx = blockIdx.x * 256 + threadIdx.x;           // unit = 8 floats
    for (; idx < 16777216; idx += 8192 * 256) {
        const float4 a = xin[idx * 2], b = xin[idx * 2 + 1];
        int4 o;
        o.x = (u32)f2bf(a.x) | ((u32)f2bf(a.y) << 16);
        o.y = (u32)f2bf(a.z) | ((u32)f2bf(a.w) << 16);
        o.z = (u32)f2bf(b.x) | ((u32)f2bf(b.y) << 16);
        o.w = (u32)f2bf(b.z) | ((u32)f2bf(b.w) << 16);
        xbf[idx] = o;
    }
}

// ---------------------------------------------------------------- prep ----
__global__ __launch_bounds__(256) void prep_kernel(
    const float* __restrict__ qkv_w, const float* __restrict__ proj_w,
    const float* __restrict__ btab, const int* __restrict__ pidx,
    u16* __restrict__ qkvw_bf, u16* __restrict__ projw_bf,
    float* __restrict__ epb)
{
    const int i = blockIdx.x * 256 + threadIdx.x;    // grid = 3072*256 = 786432
    qkvw_bf[i] = f2bf(qkv_w[i]);
    if (i < 512 * 512) projw_bf[i] = f2bf(proj_w[i]);
    if (i < 16 * 128 * 128) {
        const int rc = i & 16383, h = i >> 14;
        epb[i] = btab[pidx[rc] * 128 + 64 + h];      // bias_table[idx][TOW/2=4][h]
    }
}

// ---------------------------------------------------------------- GEMM ----
// C[M,Nn] = A[M,K] @ Bt[Nn,K]^T (+bias).  128x128 tile, BK=64, 4 waves.
// Staging: global_load_lds width16, linear LDS dest, INVERSE-swizzled global
// source (slot c16 of row r holds global col-block c16^(r&7)) -> ds_read with
// XOR swizzle is bank-conflict-free (8 addrs/bank = b128 floor).  (m97+m173)
template<bool EPI_QKV>
__global__ __launch_bounds__(256) void gemm_bt(
    const u16* __restrict__ A, const u16* __restrict__ Bt,
    const float* __restrict__ bias, void* __restrict__ Cv,
    const int Nn, const int K, const float qscale)
{
    __shared__ __attribute__((aligned(16))) u16 smem[2 * 128 * 64];
    u16* As = smem;                 // [128][64] bf16, swizzled content
    u16* Bs = smem + 128 * 64;

    const int tid = threadIdx.x;
    const int lane = tid & 63;
    const int w = tid >> 6;
    const int lo = lane & 15, g = lane >> 4;
    const int wm = w >> 1, wn = w & 1;
    const int wu = __builtin_amdgcn_readfirstlane(w);   // SGPR wave id
    const int ntile = Nn >> 7;

    int wg = blockIdx.x;
    {   // bijective XCD swizzle (gridDim % 8 == 0 for all launches)
        const int cpx = gridDim.x >> 3;
        wg = (wg & 7) * cpx + (wg >> 3);
    }
    const int bm = wg / ntile, bn = wg % ntile;
    const size_t m0 = (size_t)bm << 7;
    const int n0 = bn << 7;
    const int nk = K >> 6;

    // per-lane global source pointers: slot s = i*256+tid; r=s>>3, c16=s&7;
    // source col-block = c16 ^ (r&7)  (inverse swizzle, m173 pattern)
    const u16* pa[4];
    const u16* pb[4];
#pragma unroll
    for (int i = 0; i < 4; ++i) {
        const int s = i * 256 + tid;
        const int r = s >> 3, c16 = s & 7;
        const int csw = (c16 ^ (r & 7)) << 3;           // element offset
        pa[i] = A + (m0 + r) * (size_t)K + csw;
        pb[i] = Bt + (size_t)(n0 + r) * K + csw;
    }

    f32x4 acc[4][4] = {};

#define STAGE(kt)                                                          \
    do {                                                                   \
        const int koff = (kt) * 64;                                        \
        _Pragma("unroll")                                                  \
        for (int i = 0; i < 4; ++i)                                        \
            GLDS16(pa[i] + koff, (char*)As + i * 4096 + wu * 1024);        \
        _Pragma("unroll")                                                  \
        for (int i = 0; i < 4; ++i)                                        \
            GLDS16(pb[i] + koff, (char*)Bs + i * 4096 + wu * 1024);        \
    } while (0)

    STAGE(0);
    for (int kt = 0;;) {
        __syncthreads();            // drains vmcnt -> tile kt resident
#pragma unroll
        for (int kk = 0; kk < 2; ++kk) {
            short8 af[4], bq[4];
            const int cb = (kk * 4 + g) << 4;           // byte col-block
            const int sz = (lo & 7) << 4;               // row XOR swizzle
#pragma unroll
            for (int i = 0; i < 4; ++i) {
                const int ra = wm * 64 + i * 16 + lo;
                af[i] = *(const short8*)((const char*)As + ((ra * 128 + cb) ^ sz));
                const int rb = wn * 64 + i * 16 + lo;
                bq[i] = *(const short8*)((const char*)Bs + ((rb * 128 + cb) ^ sz));
            }
#pragma unroll
            for (int i = 0; i < 4; ++i)
#pragma unroll
                for (int j = 0; j < 4; ++j)
                    acc[i][j] = mfma16(af[i], bq[j], acc[i][j]);
        }
        if (++kt == nk) break;
        __syncthreads();            // all reads done; LDS free for next tile
        STAGE(kt);
    }
#undef STAGE

    if constexpr (EPI_QKV) {
        // restage C tile (128x128 bf16 = 32 KiB) for coalesced int4 stores
        __syncthreads();
        u16* Ct = smem;
#pragma unroll
        for (int j = 0; j < 4; ++j) {
            const int c = wn * 64 + j * 16 + lo;
            const float bv = bias[n0 + c];
            const float sc = (n0 + c < 512) ? qscale : 1.0f;
#pragma unroll
            for (int i = 0; i < 4; ++i)
#pragma unroll
                for (int ii = 0; ii < 4; ++ii) {
                    const int r = wm * 64 + i * 16 + g * 4 + ii;
                    Ct[r * 128 + c] = f2bf((acc[i][j][ii] + bv) * sc);
                }
        }
        __syncthreads();
        u16* Cg = (u16*)Cv;
#pragma unroll
        for (int it = 0; it < 8; ++it) {
            const int idx = tid + it * 256;
            const int r = idx >> 4, sgm = idx & 15;
            *(int4*)(Cg + (m0 + r) * (size_t)Nn + n0 + sgm * 8) =
                *(const int4*)(Ct + r * 128 + sgm * 8);
        }
    } else {
        float* Cg = (float*)Cv;
#pragma unroll
        for (int j = 0; j < 4; ++j) {
            const int c = wn * 64 + j * 16 + lo;
            const float bv = bias[n0 + c];
#pragma unroll
            for (int i = 0; i < 4; ++i)
#pragma unroll
                for (int ii = 0; ii < 4; ++ii) {
                    const int r = wm * 64 + i * 16 + g * 4 + ii;
                    Cg[(m0 + r) * (size_t)Nn + n0 + c] = acc[i][j][ii] + bv;
                }
        }
    }
}

// ----------------------------------------------------------- attention ----
// One block (4 waves) per (b, h). qkv layout: [b*128+n][t*512 + h*32 + d].
// Union LDS (42.5 KiB -> 3 blocks/CU): Ps overlaps Qs/Ks (dead after QK^T
// barrier), Os overlaps Vt (dead after PV barrier).
__global__ __launch_bounds__(256) void attn_kernel(
    const u16* __restrict__ qkv, const float* __restrict__ epb,
    u16* __restrict__ aout)
{
    __shared__ __attribute__((aligned(16))) char smem[43520];
    u16 (*Vt)[136]      = (u16(*)[136])smem;                 // [32][136]
    u16 (*Qs)[32]       = (u16(*)[32])(smem + 8704);         // [128][32]
    u16 (*Ks)[32]       = (u16(*)[32])(smem + 16896);        // [128][32]
    u16 (*Ps)[32][136]  = (u16(*)[32][136])(smem + 8704);    // [4][32][136]
    u16 (*Os)[32]       = (u16(*)[32])smem;                  // [128][32]

    const int h = blockIdx.x >> 11;
    const int b = blockIdx.x & 2047;
    const int tid = threadIdx.x;
    const int lane = tid & 63, w = tid >> 6;
    const int lo = lane & 15, g = lane >> 4;

    const size_t base = (size_t)b * 128 * 1536 + h * 32;
#pragma unroll
    for (int it = 0; it < 2; ++it) {
        const int s = tid + it * 256;            // 0..511
        const int n = s >> 2, c = (s & 3) * 8;
        const u16* p = qkv + base + (size_t)n * 1536 + c;
        *(int4*)(&Qs[n][c]) = *(const int4*)(p);
        *(int4*)(&Ks[n][c]) = *(const int4*)(p + 512);
        union { int4 q; u16 u[8]; } vu;
        vu.q = *(const int4*)(p + 1024);
#pragma unroll
        for (int j = 0; j < 8; ++j) Vt[c + j][n] = vu.u[j];
    }
    __syncthreads();

    const int r0 = w * 32;

    // ---- S = Q @ K^T ----
    short8 aq[2], bk[8];
    aq[0] = *(const short8*)(&Qs[r0 + lo][g * 8]);
    aq[1] = *(const short8*)(&Qs[r0 + 16 + lo][g * 8]);
#pragma unroll
    for (int j = 0; j < 8; ++j) bk[j] = *(const short8*)(&Ks[j * 16 + lo][g * 8]);

    f32x4 acc[2][8];
#pragma unroll
    for (int j = 0; j < 8; ++j) {
        f32x4 z = {0.f, 0.f, 0.f, 0.f};
        acc[0][j] = mfma16(aq[0], bk[j], z);
        acc[1][j] = mfma16(aq[1], bk[j], z);
    }

    // ---- bias + row max (pre-barrier: overlaps other waves' MFMA) ----
    const float* eb = epb + (h << 14);
    float mrow[2][4], rsum[2][4];
#pragma unroll
    for (int mt = 0; mt < 2; ++mt)
#pragma unroll
        for (int ii = 0; ii < 4; ++ii) { mrow[mt][ii] = -1e30f; rsum[mt][ii] = 0.f; }

#pragma unroll
    for (int mt = 0; mt < 2; ++mt)
#pragma unroll
        for (int j = 0; j < 8; ++j)
#pragma unroll
            for (int ii = 0; ii < 4; ++ii) {
                const int r = r0 + mt * 16 + g * 4 + ii;
                const int c = j * 16 + lo;
                const float sv = acc[mt][j][ii] + eb[(r << 7) + c];
                acc[mt][j][ii] = sv;
                mrow[mt][ii] = fmaxf(mrow[mt][ii], sv);
            }
#pragma unroll
    for (int d = 1; d < 16; d <<= 1)
#pragma unroll
        for (int mt = 0; mt < 2; ++mt)
#pragma unroll
            for (int ii = 0; ii < 4; ++ii)
                mrow[mt][ii] = fmaxf(mrow[mt][ii], __shfl_xor(mrow[mt][ii], d, 64));

    __syncthreads();   // all waves done reading Qs/Ks -> Ps may overwrite

    // ---- exp -> Ps (per-wave private region), row sums ----
#pragma unroll
    for (int mt = 0; mt < 2; ++mt)
#pragma unroll
        for (int j = 0; j < 8; ++j)
#pragma unroll
            for (int ii = 0; ii < 4; ++ii) {
                const float p = __expf(acc[mt][j][ii] - mrow[mt][ii]);
                rsum[mt][ii] += p;
                Ps[w][mt * 16 + g * 4 + ii][j * 16 + lo] = f2bf(p);
            }
#pragma unroll
    for (int d = 1; d < 16; d <<= 1)
#pragma unroll
        for (int mt = 0; mt < 2; ++mt)
#pragma unroll
            for (int ii = 0; ii < 4; ++ii)
                rsum[mt][ii] += __shfl_xor(rsum[mt][ii], d, 64);

    // ---- O = P @ V ----  (own-wave Ps; Vt shared read-only)
    f32x4 o[2][2] = {};
#pragma unroll
    for (int kk = 0; kk < 4; ++kk) {
        short8 av[2];
        av[0] = *(const short8*)(&Ps[w][lo][kk * 32 + g * 8]);
        av[1] = *(const short8*)(&Ps[w][16 + lo][kk * 32 + g * 8]);
#pragma unroll
        for (int dt = 0; dt < 2; ++dt) {
            const short8 bv = *(const short8*)(&Vt[dt * 16 + lo][kk * 32 + g * 8]);
            o[0][dt] = mfma16(av[0], bv, o[0][dt]);
            o[1][dt] = mfma16(av[1], bv, o[1][dt]);
        }
    }

    __syncthreads();   // all waves done reading Vt -> Os may overwrite

    // ---- normalize -> Os, then coalesced int4 stores ----
#pragma unroll
    for (int mt = 0; mt < 2; ++mt)
#pragma unroll
        for (int dt = 0; dt < 2; ++dt)
#pragma unroll
            for (int ii = 0; ii < 4; ++ii)
                Os[r0 + mt * 16 + g * 4 + ii][dt * 16 + lo] =
                    f2bf(o[mt][dt][ii] / rsum[mt][ii]);
    __syncthreads();

    u16* op = aout + (size_t)b * 128 * 512 + h * 32;
#pragma unroll
    for (int it = 0; it < 2; ++it) {
        const int idx = tid + it * 256;          // 0..511
        const int r = idx >> 2, c = (idx & 3) * 8;
        *(int4*)(op + (size_t)r * 512 + c) = *(const int4*)(&Os[r][c]);
    }
}

// -------------------------------------------------------------- launch ----
extern "C" void kernel_launch(void* const* d_in, const int* in_sizes, int n_in,
                              void* d_out, int out_size, void* d_ws, size_t ws_size,
                              hipStream_t stream)
{
    const float* x      = (const float*)d_in[0];
    const float* qkv_w  = (const float*)d_in[1];
    const float* qkv_b  = (const float*)d_in[2];
    const float* proj_w = (const float*)d_in[3];
    const float* proj_b = (const float*)d_in[4];
    const float* btab   = (const float*)d_in[5];
    const int*   pidx   = (const int*)d_in[6];

    // workspace layout (bytes), total 1,076,887,552 (same as round 1)
    // xbf aliases attnbuf: x_bf16 is dead before attn writes its output.
    char* ws = (char*)d_ws;
    u16*   xbf      = (u16*)(ws);                        // 268,435,456
    u16*   attnbuf  = (u16*)(ws);                        // (alias)
    u16*   qkvw_bf  = (u16*)(ws + 268435456);            //   1,572,864
    u16*   projw_bf = (u16*)(ws + 270008320);            //     524,288
    float* epb      = (float*)(ws + 270532608);          //   1,048,576
    u16*   qkvbuf   = (u16*)(ws + 271581184);            // 805,306,368

    const float qscale = 0.17677669529663687f;           // 32^-0.5

    cvt_x_kernel<<<dim3(8192), dim3(256), 0, stream>>>(
        (const float4*)x, (int4*)xbf);

    prep_kernel<<<dim3(3072), dim3(256), 0, stream>>>(
        qkv_w, proj_w, btab, pidx, qkvw_bf, projw_bf, epb);

    // QKV: [262144,512]bf16 @ [1536,512]bf16^T -> bf16 (+bias, q*scale)
    gemm_bt<true><<<dim3(2048 * 12), dim3(256), 0, stream>>>(
        xbf, qkvw_bf, qkv_b, qkvbuf, 1536, 512, qscale);

    // fused window attention: 2048 windows x 16 heads
    attn_kernel<<<dim3(32768), dim3(256), 0, stream>>>(qkvbuf, epb, attnbuf);

    // proj: [262144,512]bf16 @ [512,512]bf16^T -> f32 (+bias)
    gemm_bt<false><<<dim3(2048 * 4), dim3(256), 0, stream>>>(
        attnbuf, projw_bf, proj_b, d_out, 512, 512, 1.0f);
}